// Round 1
// baseline (668.103 us; speedup 1.0000x reference)
//
#include <hip/hip_runtime.h>
#include <math.h>

#define T_STEPS 730
#define N_GRID  8000
#define NEARZERO 1e-5f

__constant__ float c_lo[18] = {-3.f, 0.f, 0.f, 0.f, 0.f, 0.f, 0.f, 0.f, 0.005f, 1.f,    0.f, 1.f,   0.f, 1.f, 0.f, 0.f, 0.f, 0.f};
__constant__ float c_hi[18] = { 5.f, 20.f, 1.f, 1.f, 5.f, 50.f, 1.f, 1.f, 0.995f, 2000.f, 20.f, 300.f, 1.f, 5.f, 1.f, 1.f, 1.f, 1.f};

// HW transcendentals: v_exp_f32 computes 2^x, v_log_f32 computes log2(x).
#define EXP2F(v) __builtin_amdgcn_exp2f(v)
#define LOG2F(v) __builtin_amdgcn_logf(v)

// One thread per grid cell, sequential over 730 steps. 125 lone wave64s on
// 1024 SIMDs: pure dependent-chain latency bound. This revision shortens
// every per-state SELF-cycle (the scan's recurrence floor):
//   snow 3->2, xin/rstor 4->3, rechr 10->6, smav 8->4, res 12->9, gw 5->3
// via exact min/max collapses + multiplicative decay forms (same numeric
// class as the previously-verified kernel). k1 is folded into the exp2
// argument so the transcendental cycle (res) loses 2 dependent ops.
__global__ __launch_bounds__(64, 1) void prms_kernel(
    const float* __restrict__ x,       // (T, N, 3)
    const float* __restrict__ params,  // (T, N, 18) -- only slab T-1 used
    float* __restrict__ out)           // (T, N)
{
    const int i = blockIdx.x * 64 + threadIdx.x;

    const float* pp = params + ((size_t)(T_STEPS - 1) * N_GRID + (size_t)i) * 18;
    float pr[18];
#pragma unroll
    for (int j = 0; j < 18; ++j) {
        float s = 1.0f / (1.0f + expf(-pp[j]));      // precise, once
        pr[j] = c_lo[j] + s * (c_hi[j] - c_lo[j]);
    }
    const float tt = pr[0],  ddf = pr[1],  alpha = pr[2], beta = pr[3];
    const float stor = pr[4], retip = pr[5], fscn = pr[6], scx = pr[7];
    const float flz = pr[8],  stot = pr[9],  cgw = pr[10], resmax = pr[11];
    const float k1 = pr[12],  k2 = pr[13],  k3 = pr[14],  k4 = pr[15];
    const float k5 = pr[16],  k6 = pr[17];

    const float scn      = fscn * scx;
    const float remx     = (1.0f - flz) * stot;
    const float smax     = flz * stot;
    const float inv_remx = 1.0f / remx;
    const float inv_smax = 1.0f / smax;
    const float ombeta   = 1.0f - beta;
    const float omalpha  = 1.0f - alpha;
    const float omscn    = 1.0f - scn;                  // for keep-fraction clamp
    const float omk3     = 1.0f - k3;
    const float omk56    = (1.0f - k5) * (1.0f - k6);   // gw decay per step
    const float dscn     = (scx - scn) * inv_remx;      // sro slope
    // gad0 = k1*(res/resmax)^k2 = exp2(k2*log2(res) + k2*log2(1/resmax) + log2(k1))
    const float pow_c2   = fmaf(k2, LOG2F(1.0f / resmax), LOG2F(k1));

    float snow = 0.001f, xin = 0.001f, rstor = 0.001f, rechr = 0.001f;
    float smav = 0.001f, res = 0.001f, gw = 0.001f;

    constexpr int CH = 10;                // 730 = 73 * 10
    float3 buf[CH];
#pragma unroll
    for (int u = 0; u < CH; ++u) {
        const float* q = x + ((size_t)u * N_GRID + (size_t)i) * 3;
        buf[u] = make_float3(q[0], q[1], q[2]);
    }

    for (int t0 = 0; t0 < T_STEPS; t0 += CH) {
        float3 nbuf[CH];
        const int tn = t0 + CH;
        if (tn < T_STEPS) {  // uniform
#pragma unroll
            for (int u = 0; u < CH; ++u) {
                const float* q = x + ((size_t)(tn + u) * N_GRID + (size_t)i) * 3;
                nbuf[u] = make_float3(q[0], q[1], q[2]);
            }
        }

#pragma unroll
        for (int u = 0; u < CH; ++u) {
            const float PRECIP = buf[u].x;
            const float temp   = buf[u].y;
            const float Ep     = buf[u].z;

            // ---- input-only precomputation (no state deps) ----
            const bool  snowy     = (temp <= tt);
            const float flux_ps   = snowy ? PRECIP : 0.0f;
            const float flux_pr   = PRECIP - flux_ps;                // exact
            const float m0        = fmaxf(ddf * (temp - tt), 0.0f);  // melt cap
            const float ps_m      = flux_ps - m0;      // exact: one term is 0
            const float flux_pim  = flux_pr * ombeta;
            const float flux_psm  = flux_pr * beta;
            const float flux_pby  = flux_psm * omalpha;
            const float flux_pin  = flux_psm * alpha;
            const float eb        = Ep * beta;         // >= 0
            const float eim_cap   = ombeta * Ep;       // >= 0
            const float pin_eb    = flux_pin - eb;
            const float stor_eb   = stor - eb;
            const float retip_eim = retip - eim_cap;

            // ---- snow (cycle: add, max) ----
            const float snow1  = snow + flux_ps;
            const float flux_m = fminf(m0, snow1);
            snow = fmaxf(snow + ps_m, NEARZERO);       // == max(snow1 - m0, NZ)

            // ---- canopy xin (cycle: add, min, max) ----
            const float xin1     = xin + flux_pin;
            const float flux_ptf = fmaxf(xin1 - stor, 0.0f);
            const float xin2     = fmaxf(fminf(xin1, stor), NEARZERO);
            const float flux_ein = fminf(eb, xin2);
            xin = fmaxf(fminf(xin + pin_eb, stor_eb), NEARZERO);

            // ---- impervious rstor (cycle: add, min, max) ----
            const float flux_mim = flux_m * ombeta;
            const float rstor1   = rstor + (flux_mim + flux_pim);
            const float flux_sas = fmaxf(rstor1 - retip, 0.0f);
            const float rstor2   = fmaxf(fminf(rstor1, retip), NEARZERO);
            const float flux_eim = fminf(eim_cap, rstor2);
            rstor = fmaxf(fminf(rstor1 - eim_cap, retip_eim), NEARZERO);

            // ---- runoff split: keep-fraction t = 1 - sro_lin (one med3) ----
            const float flux_msm = flux_m * beta;
            const float inflow   = flux_msm + (flux_ptf + flux_pby);
            const float tkeep    = fminf(fmaxf(fmaf(-dscn, rechr, omscn), 0.0f), 1.0f);
            const float flux_inf = inflow * tkeep;
            const float flux_sro = inflow - flux_inf;

            // ---- recharge zone (cycle: fma, med3, fma, min, mul, max) ----
            const float rechr1  = fmaf(inflow, tkeep, rechr);   // rechr + inf
            const float flux_pc = fmaxf(rechr1 - remx, 0.0f);
            const float rechr2  = fminf(rechr1, remx);          // > 0
            const float ep_rem  = Ep - flux_ein - flux_eim;     // >= 0
            const float cfac    = inv_remx * ep_rem;            // >= 0
            const float emax    = rechr2 * cfac;
            const float flux_ea = fminf(emax, rechr2);
            rechr = fmaxf(rechr2 * (1.0f - cfac), NEARZERO);    // == max(rechr2-emax,NZ)

            // ---- soil moisture (cycle: add, min, mul, max) ----
            const float smav1     = smav + flux_pc;
            const float flux_excs = fmaxf(smav1 - smax, 0.0f);
            const float smav2     = fminf(smav1, smax);
            const float gfac      = inv_smax * (ep_rem - flux_ea);      // >= 0
            const float hkeep     = (rechr < ep_rem) ? (1.0f - gfac) : 1.0f;
            smav = fmaxf(smav2 * hkeep, NEARZERO);   // min(transp,smav) absorbed by NZ clamp

            // ---- reservoir (cycle: add, log2, fma, exp2, sub, max, fma, mul, max) ----
            const float flux_sep  = fminf(cgw, flux_excs);
            const float flux_qres = fmaxf(flux_excs - cgw, 0.0f);
            const float res1      = res + flux_qres;                    // > 0
            const float gad0      = EXP2F(fmaf(k2, LOG2F(res1), pow_c2));
            const float flux_gad  = fminf(gad0, res1);
            const float res2      = fmaxf(res1 - gad0, NEARZERO);
            const float ras0      = fmaf(k4, res2, k3) * res2;          // for q only
            const float flux_ras  = fminf(ras0, res2);
            res = fmaxf(res2 * fmaf(-k4, res2, omk3), NEARZERO);        // res2*(1-k3-k4*res2)

            // ---- groundwater (cycle: add, mul, max) ----
            const float gw1      = gw + (flux_gad + flux_sep);
            const float flux_bas = k5 * gw1;
            gw = fmaxf(gw1 * omk56, NEARZERO);

            const float q = (flux_sas + flux_sro) + (flux_bas + flux_ras);
            out[(size_t)(t0 + u) * N_GRID + (size_t)i] = q;
        }

#pragma unroll
        for (int u = 0; u < CH; ++u) buf[u] = nbuf[u];
    }
}

extern "C" void kernel_launch(void* const* d_in, const int* in_sizes, int n_in,
                              void* d_out, int out_size, void* d_ws, size_t ws_size,
                              hipStream_t stream) {
    const float* x      = (const float*)d_in[0];  // (730, 8000, 3)
    const float* params = (const float*)d_in[1];  // (730, 8000, 18)
    float* out          = (float*)d_out;          // (730, 8000)
    prms_kernel<<<dim3(N_GRID / 64), dim3(64), 0, stream>>>(x, params, out);
}

// Round 2
// 611.216 us; speedup vs baseline: 1.0931x; 1.0931x over previous
//
#include <hip/hip_runtime.h>
#include <math.h>

#define T_STEPS 730
#define N_GRID  8000
#define NEARZERO 1e-5f

__constant__ float c_lo[18] = {-3.f, 0.f, 0.f, 0.f, 0.f, 0.f, 0.f, 0.f, 0.005f, 1.f,    0.f, 1.f,   0.f, 1.f, 0.f, 0.f, 0.f, 0.f};
__constant__ float c_hi[18] = { 5.f, 20.f, 1.f, 1.f, 5.f, 50.f, 1.f, 1.f, 0.995f, 2000.f, 20.f, 300.f, 1.f, 5.f, 1.f, 1.f, 1.f, 1.f};

// HW transcendentals: v_exp_f32 computes 2^x, v_log_f32 computes log2(x).
#define EXP2F(v) __builtin_amdgcn_exp2f(v)
#define LOG2F(v) __builtin_amdgcn_logf(v)

// 2-wave producer/consumer pipeline per 64 cells.
//   Wave E (threads 0-63):  x loads (chunk-prefetched), input precompute,
//                           snow/xin/rstor chains -> {inflow, ep_rem, sas}
//   Wave L (threads 64-127): rechr/smav/res/gw chains, q, out stores.
// Handoff: 3 floats/step/lane via double-buffered LDS chunks; one uniform
// __syncthreads per chunk (74 barriers). Rationale: a single in-order wave
// serializes the ~80-op step DAG at ~500 cyc/step; splitting halves each
// wave's program and runs the halves concurrently on different SIMDs.
// Arithmetic per value is identical to the previously verified kernel.
constexpr int CH  = 10;            // chunk size; 730 = 73 * 10
constexpr int NCH = T_STEPS / CH;  // 73

__global__ __launch_bounds__(128, 1) void prms_kernel(
    const float* __restrict__ x,       // (T, N, 3)
    const float* __restrict__ params,  // (T, N, 18) -- only slab T-1 used
    float* __restrict__ out)           // (T, N)
{
    const int lane = threadIdx.x & 63;
    const int wv   = threadIdx.x >> 6;          // 0 = producer, 1 = consumer
    const int i    = blockIdx.x * 64 + lane;

    // handoff: [buffer][step-in-chunk][lane] = {inflow, ep_rem, sas, pad}
    __shared__ float4 hx[2][CH][64];            // 20 KiB

    const float* pp = params + ((size_t)(T_STEPS - 1) * N_GRID + (size_t)i) * 18;
    float pr[18];
#pragma unroll
    for (int j = 0; j < 18; ++j) {
        float s = 1.0f / (1.0f + expf(-pp[j]));      // precise, once
        pr[j] = c_lo[j] + s * (c_hi[j] - c_lo[j]);
    }

    if (wv == 0) {
        // ---------------- producer wave ----------------
        const float tt = pr[0],  ddf = pr[1], alpha = pr[2], beta = pr[3];
        const float stor = pr[4], retip = pr[5];
        const float ombeta  = 1.0f - beta;
        const float omalpha = 1.0f - alpha;

        float snow = 0.001f, xin = 0.001f, rstor = 0.001f;

        float3 buf[CH];
#pragma unroll
        for (int u = 0; u < CH; ++u) {
            const float* q = x + ((size_t)u * N_GRID + (size_t)i) * 3;
            buf[u] = make_float3(q[0], q[1], q[2]);
        }

        for (int c = 0; c <= NCH; ++c) {
            if (c < NCH) {
                float3 nbuf[CH];
                if (c + 1 < NCH) {   // uniform
#pragma unroll
                    for (int u = 0; u < CH; ++u) {
                        const float* q = x + ((size_t)((c + 1) * CH + u) * N_GRID + (size_t)i) * 3;
                        nbuf[u] = make_float3(q[0], q[1], q[2]);
                    }
                }

#pragma unroll
                for (int u = 0; u < CH; ++u) {
                    const float PRECIP = buf[u].x;
                    const float temp   = buf[u].y;
                    const float Ep     = buf[u].z;

                    // ---- input-only precomputation ----
                    const bool  snowy     = (temp <= tt);
                    const float flux_ps   = snowy ? PRECIP : 0.0f;
                    const float flux_pr   = PRECIP - flux_ps;                // exact
                    const float m0        = fmaxf(ddf * (temp - tt), 0.0f);
                    const float ps_m      = flux_ps - m0;      // exact: one term is 0
                    const float flux_pim  = flux_pr * ombeta;
                    const float flux_psm  = flux_pr * beta;
                    const float flux_pby  = flux_psm * omalpha;
                    const float flux_pin  = flux_psm * alpha;
                    const float eb        = Ep * beta;
                    const float eim_cap   = ombeta * Ep;
                    const float pin_eb    = flux_pin - eb;
                    const float stor_eb   = stor - eb;
                    const float retip_eim = retip - eim_cap;

                    // ---- snow ----
                    const float snow1  = snow + flux_ps;
                    const float flux_m = fminf(m0, snow1);
                    snow = fmaxf(snow + ps_m, NEARZERO);

                    // ---- canopy xin ----
                    const float xin1     = xin + flux_pin;
                    const float flux_ptf = fmaxf(xin1 - stor, 0.0f);
                    const float xin2     = fmaxf(fminf(xin1, stor), NEARZERO);
                    const float flux_ein = fminf(eb, xin2);
                    xin = fmaxf(fminf(xin + pin_eb, stor_eb), NEARZERO);

                    // ---- impervious rstor ----
                    const float flux_mim = flux_m * ombeta;
                    const float rstor1   = rstor + (flux_mim + flux_pim);
                    const float flux_sas = fmaxf(rstor1 - retip, 0.0f);
                    const float rstor2   = fmaxf(fminf(rstor1, retip), NEARZERO);
                    const float flux_eim = fminf(eim_cap, rstor2);
                    rstor = fmaxf(fminf(rstor1 - eim_cap, retip_eim), NEARZERO);

                    // ---- handoff values ----
                    const float flux_msm = flux_m * beta;
                    const float inflow   = flux_msm + (flux_ptf + flux_pby);
                    const float ep_rem   = Ep - flux_ein - flux_eim;
                    hx[c & 1][u][lane] = make_float4(inflow, ep_rem, flux_sas, 0.0f);
                }

                if (c + 1 < NCH) {
                    float3 nbuf[CH];
#pragma unroll
                    for (int u = 0; u < CH; ++u) {
                        const float* q = x + ((size_t)((c + 1) * CH + u) * N_GRID + (size_t)i) * 3;
                        nbuf[u] = make_float3(q[0], q[1], q[2]);
                    }
#pragma unroll
                    for (int u = 0; u < CH; ++u) buf[u] = nbuf[u];
                }
            }
            __syncthreads();
        }
    } else {
        // ---------------- consumer wave ----------------
        const float fscn = pr[6], scx = pr[7], flz = pr[8], stot = pr[9];
        const float cgw = pr[10], resmax = pr[11];
        const float k1 = pr[12], k2 = pr[13], k3 = pr[14], k4 = pr[15];
        const float k5 = pr[16], k6 = pr[17];

        const float scn      = fscn * scx;
        const float remx     = (1.0f - flz) * stot;
        const float smax     = flz * stot;
        const float inv_remx = 1.0f / remx;
        const float inv_smax = 1.0f / smax;
        const float omscn    = 1.0f - scn;
        const float omk3     = 1.0f - k3;
        const float omk56    = (1.0f - k5) * (1.0f - k6);
        const float dscn     = (scx - scn) * inv_remx;
        const float pow_c2   = fmaf(k2, LOG2F(1.0f / resmax), LOG2F(k1));

        float rechr = 0.001f, smav = 0.001f, res = 0.001f, gw = 0.001f;

        for (int c = 0; c <= NCH; ++c) {
            if (c > 0) {
                const int cc = c - 1;
#pragma unroll
                for (int u = 0; u < CH; ++u) {
                    const float4 h = hx[cc & 1][u][lane];
                    const float inflow   = h.x;
                    const float ep_rem   = h.y;
                    const float flux_sas = h.z;

                    // ---- runoff split ----
                    const float tkeep    = fminf(fmaxf(fmaf(-dscn, rechr, omscn), 0.0f), 1.0f);
                    const float flux_inf = inflow * tkeep;
                    const float flux_sro = inflow - flux_inf;

                    // ---- recharge zone ----
                    const float rechr1  = fmaf(inflow, tkeep, rechr);
                    const float flux_pc = fmaxf(rechr1 - remx, 0.0f);
                    const float rechr2  = fminf(rechr1, remx);
                    const float cfac    = inv_remx * ep_rem;
                    const float emax    = rechr2 * cfac;
                    const float flux_ea = fminf(emax, rechr2);
                    rechr = fmaxf(rechr2 * (1.0f - cfac), NEARZERO);

                    // ---- soil moisture ----
                    const float smav1     = smav + flux_pc;
                    const float flux_excs = fmaxf(smav1 - smax, 0.0f);
                    const float smav2     = fminf(smav1, smax);
                    const float gfac      = inv_smax * (ep_rem - flux_ea);
                    const float hkeep     = (rechr < ep_rem) ? (1.0f - gfac) : 1.0f;
                    smav = fmaxf(smav2 * hkeep, NEARZERO);

                    // ---- reservoir ----
                    const float flux_sep  = fminf(cgw, flux_excs);
                    const float flux_qres = fmaxf(flux_excs - cgw, 0.0f);
                    const float res1      = res + flux_qres;
                    const float gad0      = EXP2F(fmaf(k2, LOG2F(res1), pow_c2));
                    const float flux_gad  = fminf(gad0, res1);
                    const float res2      = fmaxf(res1 - gad0, NEARZERO);
                    const float ras0      = fmaf(k4, res2, k3) * res2;
                    const float flux_ras  = fminf(ras0, res2);
                    res = fmaxf(res2 * fmaf(-k4, res2, omk3), NEARZERO);

                    // ---- groundwater ----
                    const float gw1      = gw + (flux_gad + flux_sep);
                    const float flux_bas = k5 * gw1;
                    gw = fmaxf(gw1 * omk56, NEARZERO);

                    const float q = (flux_sas + flux_sro) + (flux_bas + flux_ras);
                    out[(size_t)(cc * CH + u) * N_GRID + (size_t)i] = q;
                }
            }
            __syncthreads();
        }
    }
}

extern "C" void kernel_launch(void* const* d_in, const int* in_sizes, int n_in,
                              void* d_out, int out_size, void* d_ws, size_t ws_size,
                              hipStream_t stream) {
    const float* x      = (const float*)d_in[0];  // (730, 8000, 3)
    const float* params = (const float*)d_in[1];  // (730, 8000, 18)
    float* out          = (float*)d_out;          // (730, 8000)
    prms_kernel<<<dim3(N_GRID / 64), dim3(128), 0, stream>>>(x, params, out);
}

// Round 3
// 597.743 us; speedup vs baseline: 1.1177x; 1.0225x over previous
//
#include <hip/hip_runtime.h>
#include <math.h>

#define T_STEPS 730
#define N_GRID  8000
#define NEARZERO 1e-5f

__constant__ float c_lo[18] = {-3.f, 0.f, 0.f, 0.f, 0.f, 0.f, 0.f, 0.f, 0.005f, 1.f,    0.f, 1.f,   0.f, 1.f, 0.f, 0.f, 0.f, 0.f};
__constant__ float c_hi[18] = { 5.f, 20.f, 1.f, 1.f, 5.f, 50.f, 1.f, 1.f, 0.995f, 2000.f, 20.f, 300.f, 1.f, 5.f, 1.f, 1.f, 1.f, 1.f};

// HW transcendentals: v_exp_f32 computes 2^x, v_log_f32 computes log2(x).
#define EXP2F(v) __builtin_amdgcn_exp2f(v)
#define LOG2F(v) __builtin_amdgcn_logf(v)

// 4-wave pipeline per 64 cells (one wave per SIMD of the CU):
//   W0: x loads (chunk-prefetched) + input precompute + snow
//   W1: canopy xin + impervious rstor          (needs 7 floats from W0)
//   W2: runoff split + recharge + soil moisture (needs 3 floats from W1)
//   W3: reservoir + groundwater + q + store     (needs 2 floats from W2)
// Rationale: lone in-order waves serialize the step DAG at ~issue+latency
// per op; the 2-wave split (R2) cut the kernel ~153->~96us. Per-wave
// program length is still the clock (~40 ops on the consumer). The DAG has
// two more narrow cuts, so split into 4 concurrent waves (~16/22/25/23
// ops/step each). Handoffs via double-buffered LDS chunks, one barrier per
// superstep, pipeline skew = 3 chunks of 76. Arithmetic is op-for-op
// identical to the verified R2 kernel (absmax 0.125).
constexpr int CH  = 10;            // chunk size; 730 = 73 * 10
constexpr int NCH = T_STEPS / CH;  // 73

__global__ __launch_bounds__(256, 1) void prms_kernel(
    const float* __restrict__ x,       // (T, N, 3)
    const float* __restrict__ params,  // (T, N, 18) -- only slab T-1 used
    float* __restrict__ out)           // (T, N)
{
    const int lane = threadIdx.x & 63;
    const int wv   = threadIdx.x >> 6;          // 0..3 pipeline stage
    const int i    = blockIdx.x * 64 + lane;

    // double-buffered handoff chunks [buf][step-in-chunk][lane]
    __shared__ float4 c0a[2][CH][64];   // {flux_pin, eb, rin, eim_cap}   20 KiB
    __shared__ float4 c0b[2][CH][64];   // {msm, pby, Ep, -}              20 KiB
    __shared__ float4 c1 [2][CH][64];   // {inflow, ep_rem, sas, -}       20 KiB
    __shared__ float2 c2 [2][CH][64];   // {flux_excs, sas+sro}           10 KiB

    const float* pp = params + ((size_t)(T_STEPS - 1) * N_GRID + (size_t)i) * 18;
    float pr[18];
#pragma unroll
    for (int j = 0; j < 18; ++j) {
        float s = 1.0f / (1.0f + expf(-pp[j]));      // precise, once
        pr[j] = c_lo[j] + s * (c_hi[j] - c_lo[j]);
    }
    const float tt = pr[0],  ddf = pr[1], alpha = pr[2], beta = pr[3];
    const float stor = pr[4], retip = pr[5], fscn = pr[6], scx = pr[7];
    const float flz = pr[8],  stot = pr[9], cgw = pr[10], resmax = pr[11];
    const float k1 = pr[12],  k2 = pr[13], k3 = pr[14], k4 = pr[15];
    const float k5 = pr[16],  k6 = pr[17];

    const float ombeta   = 1.0f - beta;
    const float omalpha  = 1.0f - alpha;
    const float scn      = fscn * scx;
    const float remx     = (1.0f - flz) * stot;
    const float smax     = flz * stot;
    const float inv_remx = 1.0f / remx;
    const float inv_smax = 1.0f / smax;
    const float omscn    = 1.0f - scn;
    const float omk3     = 1.0f - k3;
    const float omk56    = (1.0f - k5) * (1.0f - k6);
    const float dscn     = (scx - scn) * inv_remx;
    const float pow_c2   = fmaf(k2, LOG2F(1.0f / resmax), LOG2F(k1));

    if (wv == 0) {
        // ---------------- W0: loads + precompute + snow ----------------
        float snow = 0.001f;
        float3 buf[CH];
#pragma unroll
        for (int u = 0; u < CH; ++u) {
            const float* q = x + ((size_t)u * N_GRID + (size_t)i) * 3;
            buf[u] = make_float3(q[0], q[1], q[2]);
        }

        for (int c = 0; c < NCH + 3; ++c) {
            if (c < NCH) {
                float3 nbuf[CH];
                const bool more = (c + 1 < NCH);    // uniform
                if (more) {
#pragma unroll
                    for (int u = 0; u < CH; ++u) {
                        const float* q = x + ((size_t)((c + 1) * CH + u) * N_GRID + (size_t)i) * 3;
                        nbuf[u] = make_float3(q[0], q[1], q[2]);
                    }
                }

#pragma unroll
                for (int u = 0; u < CH; ++u) {
                    const float PRECIP = buf[u].x;
                    const float temp   = buf[u].y;
                    const float Ep     = buf[u].z;

                    const bool  snowy    = (temp <= tt);
                    const float flux_ps  = snowy ? PRECIP : 0.0f;
                    const float flux_pr  = PRECIP - flux_ps;               // exact
                    const float m0       = fmaxf(ddf * (temp - tt), 0.0f);
                    const float ps_m     = flux_ps - m0;    // exact: one term is 0

                    const float snow1  = snow + flux_ps;
                    const float flux_m = fminf(m0, snow1);
                    snow = fmaxf(snow + ps_m, NEARZERO);

                    const float flux_pim = flux_pr * ombeta;
                    const float flux_psm = flux_pr * beta;
                    const float flux_pby = flux_psm * omalpha;
                    const float flux_pin = flux_psm * alpha;
                    const float eb       = Ep * beta;
                    const float eim_cap  = ombeta * Ep;
                    const float flux_mim = flux_m * ombeta;
                    const float rin      = flux_mim + flux_pim;
                    const float msm      = flux_m * beta;

                    c0a[c & 1][u][lane] = make_float4(flux_pin, eb, rin, eim_cap);
                    c0b[c & 1][u][lane] = make_float4(msm, flux_pby, Ep, 0.0f);
                }

                if (more) {
#pragma unroll
                    for (int u = 0; u < CH; ++u) buf[u] = nbuf[u];
                }
            }
            __syncthreads();
        }
    } else if (wv == 1) {
        // ---------------- W1: canopy xin + impervious rstor ----------------
        float xin = 0.001f, rstor = 0.001f;

        for (int c = 0; c < NCH + 3; ++c) {
            const int cc = c - 1;
            if (cc >= 0 && cc < NCH) {
#pragma unroll
                for (int u = 0; u < CH; ++u) {
                    const float4 a = c0a[cc & 1][u][lane];
                    const float4 b = c0b[cc & 1][u][lane];
                    const float flux_pin = a.x, eb = a.y, rin = a.z, eim_cap = a.w;
                    const float msm = b.x, pby = b.y, Ep = b.z;

                    const float pin_eb    = flux_pin - eb;
                    const float stor_eb   = stor - eb;
                    const float retip_eim = retip - eim_cap;

                    const float xin1     = xin + flux_pin;
                    const float flux_ptf = fmaxf(xin1 - stor, 0.0f);
                    const float xin2     = fmaxf(fminf(xin1, stor), NEARZERO);
                    const float flux_ein = fminf(eb, xin2);
                    xin = fmaxf(fminf(xin + pin_eb, stor_eb), NEARZERO);

                    const float rstor1   = rstor + rin;
                    const float flux_sas = fmaxf(rstor1 - retip, 0.0f);
                    const float rstor2   = fmaxf(fminf(rstor1, retip), NEARZERO);
                    const float flux_eim = fminf(eim_cap, rstor2);
                    rstor = fmaxf(fminf(rstor1 - eim_cap, retip_eim), NEARZERO);

                    const float inflow = msm + (flux_ptf + pby);
                    const float ep_rem = Ep - flux_ein - flux_eim;
                    c1[cc & 1][u][lane] = make_float4(inflow, ep_rem, flux_sas, 0.0f);
                }
            }
            __syncthreads();
        }
    } else if (wv == 2) {
        // ---------------- W2: runoff split + recharge + soil ----------------
        float rechr = 0.001f, smav = 0.001f;

        for (int c = 0; c < NCH + 3; ++c) {
            const int cc = c - 2;
            if (cc >= 0 && cc < NCH) {
#pragma unroll
                for (int u = 0; u < CH; ++u) {
                    const float4 h = c1[cc & 1][u][lane];
                    const float inflow = h.x, ep_rem = h.y, flux_sas = h.z;

                    const float tkeep    = fminf(fmaxf(fmaf(-dscn, rechr, omscn), 0.0f), 1.0f);
                    const float flux_inf = inflow * tkeep;
                    const float flux_sro = inflow - flux_inf;

                    const float rechr1  = fmaf(inflow, tkeep, rechr);
                    const float flux_pc = fmaxf(rechr1 - remx, 0.0f);
                    const float rechr2  = fminf(rechr1, remx);
                    const float cfac    = inv_remx * ep_rem;
                    const float emax    = rechr2 * cfac;
                    const float flux_ea = fminf(emax, rechr2);
                    rechr = fmaxf(rechr2 * (1.0f - cfac), NEARZERO);

                    const float smav1     = smav + flux_pc;
                    const float flux_excs = fmaxf(smav1 - smax, 0.0f);
                    const float smav2     = fminf(smav1, smax);
                    const float gfac      = inv_smax * (ep_rem - flux_ea);
                    const float hkeep     = (rechr < ep_rem) ? (1.0f - gfac) : 1.0f;
                    smav = fmaxf(smav2 * hkeep, NEARZERO);

                    const float s2 = flux_sas + flux_sro;
                    c2[cc & 1][u][lane] = make_float2(flux_excs, s2);
                }
            }
            __syncthreads();
        }
    } else {
        // ---------------- W3: reservoir + groundwater + q ----------------
        float res = 0.001f, gw = 0.001f;

        for (int c = 0; c < NCH + 3; ++c) {
            const int cc = c - 3;
            if (cc >= 0 && cc < NCH) {
#pragma unroll
                for (int u = 0; u < CH; ++u) {
                    const float2 h = c2[cc & 1][u][lane];
                    const float flux_excs = h.x, s2 = h.y;

                    const float flux_sep  = fminf(cgw, flux_excs);
                    const float flux_qres = fmaxf(flux_excs - cgw, 0.0f);
                    const float res1      = res + flux_qres;
                    const float gad0      = EXP2F(fmaf(k2, LOG2F(res1), pow_c2));
                    const float flux_gad  = fminf(gad0, res1);
                    const float res2      = fmaxf(res1 - gad0, NEARZERO);
                    const float ras0      = fmaf(k4, res2, k3) * res2;
                    const float flux_ras  = fminf(ras0, res2);
                    res = fmaxf(res2 * fmaf(-k4, res2, omk3), NEARZERO);

                    const float gw1      = gw + (flux_gad + flux_sep);
                    const float flux_bas = k5 * gw1;
                    gw = fmaxf(gw1 * omk56, NEARZERO);

                    const float q = s2 + (flux_bas + flux_ras);
                    out[(size_t)(cc * CH + u) * N_GRID + (size_t)i] = q;
                }
            }
            __syncthreads();
        }
    }
}

extern "C" void kernel_launch(void* const* d_in, const int* in_sizes, int n_in,
                              void* d_out, int out_size, void* d_ws, size_t ws_size,
                              hipStream_t stream) {
    const float* x      = (const float*)d_in[0];  // (730, 8000, 3)
    const float* params = (const float*)d_in[1];  // (730, 8000, 18)
    float* out          = (float*)d_out;          // (730, 8000)
    prms_kernel<<<dim3(N_GRID / 64), dim3(256), 0, stream>>>(x, params, out);
}